// Round 1
// baseline (1035.575 us; speedup 1.0000x reference)
//
#include <hip/hip_runtime.h>
#include <math.h>

// Mean-shift: x in R^{32 x 8192}, 5 iterations of
//   K = exp(0.5 * x^T x); deg = colsum(K); x = 0.5 * (x @ K)/deg + 0.5 * x
// fp32 vector baseline. x kept transposed [N][32] so x[:,i] is wave-uniform
// (broadcast LDS reads). i-range split into S chunks for occupancy; partial
// (y, deg) per chunk reduced in a second kernel.

#define N_PIX 8192
#define DIM 32
#define STEP 0.5f
#define OMS  0.5f   // 1 - STEP
#define BW 0.5f
#define NITER 5
#define TI 64       // i's per LDS tile

// --- transpose [32][8192] -> [8192][32] ---
__global__ __launch_bounds__(256) void k_tr(const float* __restrict__ x,
                                            float* __restrict__ xt) {
    int t = blockIdx.x * 256 + threadIdx.x;      // 0..262143
    int d = t >> 13;                             // /8192
    int i = t & (N_PIX - 1);
    xt[(size_t)i * DIM + d] = x[t];
}

// --- main pair kernel: partial y[32], deg over one i-chunk, one j/thread ---
__global__ __launch_bounds__(256) void k_pairs(const float* __restrict__ xt,
                                               float* __restrict__ part,
                                               int tilesPerChunk) {
    __shared__ float smem[TI * DIM];             // 8 KB, [ii][d] linear
    const int j = blockIdx.x * 256 + threadIdx.x;
    const int chunk = blockIdx.y;

    // own column x[:,j] -> registers
    float xj[DIM];
    const float4* xjp = (const float4*)(xt + (size_t)j * DIM);
#pragma unroll
    for (int q = 0; q < 8; ++q) {
        float4 v = xjp[q];
        xj[4*q+0] = v.x; xj[4*q+1] = v.y; xj[4*q+2] = v.z; xj[4*q+3] = v.w;
    }

    float acc[DIM];
#pragma unroll
    for (int d = 0; d < DIM; ++d) acc[d] = 0.f;
    float deg = 0.f;

    const int t0 = chunk * tilesPerChunk;
    for (int t = 0; t < tilesPerChunk; ++t) {
        const int i0 = (t0 + t) * TI;
        // stage 8 KB tile (contiguous in xt) into LDS, coalesced b128
        const float4* g = (const float4*)(xt + (size_t)i0 * DIM);
        float4* s4 = (float4*)smem;
#pragma unroll
        for (int k = 0; k < (TI * DIM / 4) / 256; ++k)
            s4[threadIdx.x + 256 * k] = g[threadIdx.x + 256 * k];
        __syncthreads();

#pragma unroll 2
        for (int ii = 0; ii < TI; ++ii) {
            // broadcast reads: same address across all lanes
            const float4* r = (const float4*)(smem + ii * DIM);
            float a[DIM];
#pragma unroll
            for (int q = 0; q < 8; ++q) {
                float4 v = r[q];
                a[4*q+0] = v.x; a[4*q+1] = v.y; a[4*q+2] = v.z; a[4*q+3] = v.w;
            }
            // dot, 4 independent chains
            float s0 = 0.f, s1 = 0.f, s2 = 0.f, s3 = 0.f;
#pragma unroll
            for (int d = 0; d < DIM; d += 4) {
                s0 = fmaf(a[d+0], xj[d+0], s0);
                s1 = fmaf(a[d+1], xj[d+1], s1);
                s2 = fmaf(a[d+2], xj[d+2], s2);
                s3 = fmaf(a[d+3], xj[d+3], s3);
            }
            float w = __expf(BW * ((s0 + s1) + (s2 + s3)));
            deg += w;
#pragma unroll
            for (int d = 0; d < DIM; ++d) acc[d] = fmaf(w, a[d], acc[d]);
        }
        __syncthreads();
    }

    // partials: part[(chunk*33 + r)*N + j], r=0..31 -> y_d, r=32 -> deg
    size_t base = (size_t)chunk * (DIM + 1) * N_PIX + j;
#pragma unroll
    for (int d = 0; d < DIM; ++d) part[base + (size_t)d * N_PIX] = acc[d];
    part[base + (size_t)DIM * N_PIX] = deg;
}

// --- reduce chunks + blend; write xt-layout (mid iters) or [D][N] (last) ---
__global__ __launch_bounds__(256) void k_reduce(const float* __restrict__ part,
                                                const float* __restrict__ xt,
                                                float* __restrict__ out,
                                                int S, int last) {
    const int j = blockIdx.x * 256 + threadIdx.x;
    float y[DIM];
#pragma unroll
    for (int d = 0; d < DIM; ++d) y[d] = 0.f;
    float deg = 0.f;
    for (int c = 0; c < S; ++c) {
        size_t base = (size_t)c * (DIM + 1) * N_PIX + j;
#pragma unroll
        for (int d = 0; d < DIM; ++d) y[d] += part[base + (size_t)d * N_PIX];
        deg += part[base + (size_t)DIM * N_PIX];
    }
    const float inv = STEP / deg;
    const float4* xc = (const float4*)(xt + (size_t)j * DIM);
    if (last) {
#pragma unroll
        for (int q = 0; q < 8; ++q) {
            float4 v = xc[q];
            out[(size_t)(4*q+0) * N_PIX + j] = fmaf(y[4*q+0], inv, OMS * v.x);
            out[(size_t)(4*q+1) * N_PIX + j] = fmaf(y[4*q+1], inv, OMS * v.y);
            out[(size_t)(4*q+2) * N_PIX + j] = fmaf(y[4*q+2], inv, OMS * v.z);
            out[(size_t)(4*q+3) * N_PIX + j] = fmaf(y[4*q+3], inv, OMS * v.w);
        }
    } else {
        float4* o = (float4*)(out + (size_t)j * DIM);
#pragma unroll
        for (int q = 0; q < 8; ++q) {
            float4 v = xc[q];
            float4 w;
            w.x = fmaf(y[4*q+0], inv, OMS * v.x);
            w.y = fmaf(y[4*q+1], inv, OMS * v.y);
            w.z = fmaf(y[4*q+2], inv, OMS * v.z);
            w.w = fmaf(y[4*q+3], inv, OMS * v.w);
            o[q] = w;
        }
    }
}

extern "C" void kernel_launch(void* const* d_in, const int* in_sizes, int n_in,
                              void* d_out, int out_size, void* d_ws, size_t ws_size,
                              hipStream_t stream) {
    const float* x_in = (const float*)d_in[0];
    float* out = (float*)d_out;

    const size_t nd = (size_t)N_PIX * DIM;
    float* A = (float*)d_ws;
    float* B = A + nd;
    float* P = B + nd;

    // pick i-chunk count S (power of 2, <=32) that fits the workspace
    size_t availFloats = (ws_size / 4 > 2 * nd) ? (ws_size / 4 - 2 * nd) : 0;
    int S = 32;
    while (S > 1 && (size_t)S * (DIM + 1) * N_PIX > availFloats) S >>= 1;
    const int tilesPerChunk = (N_PIX / TI) / S;   // 128 / S

    k_tr<<<(int)(nd / 256), 256, 0, stream>>>(x_in, A);

    float* cur = A;
    float* nxt = B;
    for (int it = 0; it < NITER; ++it) {
        const int last = (it == NITER - 1);
        k_pairs<<<dim3(N_PIX / 256, S), 256, 0, stream>>>(cur, P, tilesPerChunk);
        k_reduce<<<N_PIX / 256, 256, 0, stream>>>(P, cur, last ? out : nxt, S, last);
        float* tmp = cur; cur = nxt; nxt = tmp;
    }
}

// Round 2
// 164.643 us; speedup vs baseline: 6.2898x; 6.2898x over previous
//
#include <hip/hip_runtime.h>
#include <hip/hip_bf16.h>
#include <math.h>

// Mean-shift as attention: per iter, out[:,j] = sum_i exp(0.5 q_j.k_i) x_i / deg_j,
// blended 0.5/0.5 with x. Q=K scaled by ALPHA=sqrt(0.5*log2(e)) in bf16 so the
// inner loop needs only exp2. Swapped QK^T (mfma(K,Q)) -> P lane-local ->
// cvt_pk+permlane32_swap -> PV mfma. All MFMA operands live in pre-permuted
// fragment-order global arrays: [iblk32][ks][hi][row32][8 bf16] (2KB/iblk),
// so staging is linear and ds_read_b128 is conflict-free.

typedef short bf16x8 __attribute__((ext_vector_type(8)));
typedef float f32x16 __attribute__((ext_vector_type(16)));
typedef int v2i __attribute__((ext_vector_type(2)));

#define NPIX 8192
#define DIM 32
#define NITER 5
#define SCH 8                 // i-chunks (grid.y)
#define CHUNK (NPIX / SCH)    // 1024 i per WG
#define HALF 512              // i per LDS stage
#define WAVES 4               // waves per WG (128 j per WG)
#define PSTR 36               // partial row stride (32 y + deg + pad, 16B aligned)
#define ALPHA 0.8493219f      // sqrt(0.5 * log2(e))

#if __has_builtin(__builtin_amdgcn_exp2f)
#define EXP2(x) __builtin_amdgcn_exp2f(x)
#else
#define EXP2(x) exp2f(x)
#endif

__device__ inline unsigned cvtpk(float lo, float hi) {
    unsigned r;
    asm("v_cvt_pk_bf16_f32 %0, %1, %2" : "=v"(r) : "v"(lo), "v"(hi));
    return r;
}

__device__ inline void swap32(unsigned a, unsigned b, unsigned& x, unsigned& y) {
#if __has_builtin(__builtin_amdgcn_permlane32_swap)
    v2i r = __builtin_amdgcn_permlane32_swap((int)a, (int)b, false, false);
    x = (unsigned)r.x;  // lanes<32: a ; lanes>=32: b[lane-32]
    y = (unsigned)r.y;  // lanes<32: a[lane+32] ; lanes>=32: b
#else
    unsigned bs = __shfl_xor(b, 32);
    unsigned as = __shfl_xor(a, 32);
    int hi = (int)(threadIdx.x & 63) >> 5;
    x = hi ? bs : a;
    y = hi ? b : as;
#endif
}

__device__ inline unsigned short f2bf(float f) {  // RNE
    unsigned u = __float_as_uint(f);
    unsigned r = (u + 0x7FFFu + ((u >> 16) & 1u)) >> 16;
    return (unsigned short)r;
}

union U4 { uint4 q; bf16x8 v; };

// ---------------- main pair kernel ----------------
__global__ __launch_bounds__(256, 2) void k_ms(const unsigned short* __restrict__ kq,
                                               const unsigned short* __restrict__ vv,
                                               float* __restrict__ part) {
    __shared__ uint4 sm[4096];  // K tiles [0,2048), V tiles [2048,4096)  = 64 KB
    const int tid = threadIdx.x;
    const int lane = tid & 63;
    const int lo = lane & 31, hi = lane >> 5;
    const int wv = tid >> 6;
    const int jblk = blockIdx.x * WAVES + wv;   // 0..255
    const int chunk = blockIdx.y;               // 0..7

    const uint4* kq4 = (const uint4*)kq;
    const uint4* vv4 = (const uint4*)vv;
    const int lbase = hi * 32 + lo;             // fragment read offset (uint4 units)

    // Q fragments (B-operand): lane holds col j=lo, k-elems d = ks*16 + hi*8 + e
    U4 q0, q1;
    q0.q = kq4[jblk * 128 + lbase];
    q1.q = kq4[jblk * 128 + 64 + lbase];

    f32x16 y;
#pragma unroll
    for (int r = 0; r < 16; ++r) y[r] = 0.f;
    float deg = 0.f;

    for (int h = 0; h < 2; ++h) {
        __syncthreads();
        const int ibase = chunk * CHUNK + h * HALF;
        const uint4* gk = kq4 + (size_t)ibase * 4;   // 64 B per i
        const uint4* gv = vv4 + (size_t)ibase * 4;
        uint4 tk[8];
#pragma unroll
        for (int r = 0; r < 8; ++r) tk[r] = gk[r * 256 + tid];
#pragma unroll
        for (int r = 0; r < 8; ++r) sm[r * 256 + tid] = tk[r];
        uint4 tv[8];
#pragma unroll
        for (int r = 0; r < 8; ++r) tv[r] = gv[r * 256 + tid];
#pragma unroll
        for (int r = 0; r < 8; ++r) sm[2048 + r * 256 + tid] = tv[r];
        __syncthreads();

#pragma unroll
        for (int it = 0; it < 16; ++it) {
            U4 ka0, ka1, vb0, vb1;
            ka0.q = sm[it * 128 + lbase];
            ka1.q = sm[it * 128 + 64 + lbase];
            vb0.q = sm[2048 + it * 128 + lbase];
            vb1.q = sm[2048 + it * 128 + 64 + lbase];

            f32x16 s;
#pragma unroll
            for (int r = 0; r < 16; ++r) s[r] = 0.f;
            s = __builtin_amdgcn_mfma_f32_32x32x16_bf16(ka0.v, q0.v, s, 0, 0, 0);
            s = __builtin_amdgcn_mfma_f32_32x32x16_bf16(ka1.v, q1.v, s, 0, 0, 0);
            // lane holds P[i=crow(r,hi), j=lo], crow = (r&3) + 8*(r>>2) + 4*hi
            float p[16];
#pragma unroll
            for (int r = 0; r < 16; ++r) p[r] = EXP2(s[r]);

            float d0 = (p[0] + p[1]) + (p[2] + p[3]);
            float d1 = (p[4] + p[5]) + (p[6] + p[7]);
            float d2 = (p[8] + p[9]) + (p[10] + p[11]);
            float d3 = (p[12] + p[13]) + (p[14] + p[15]);
            deg += (d0 + d1) + (d2 + d3);

#pragma unroll
            for (int ks = 0; ks < 2; ++ks) {
                const float* pb = p + ks * 8;
                unsigned a0 = cvtpk(pb[0], pb[1]);
                unsigned a1 = cvtpk(pb[2], pb[3]);
                unsigned b0 = cvtpk(pb[4], pb[5]);
                unsigned b1 = cvtpk(pb[6], pb[7]);
                unsigned w01, w45, w23, w67;
                swap32(a0, b0, w01, w45);
                swap32(a1, b1, w23, w67);
                U4 pa;
                pa.q = make_uint4(w01, w23, w45, w67);
                y = __builtin_amdgcn_mfma_f32_32x32x16_bf16(
                        pa.v, (ks ? vb1.v : vb0.v), y, 0, 0, 0);
            }
        }
    }

    deg += __shfl_xor(deg, 32);

    float* prow = part + ((size_t)chunk * NPIX + (size_t)jblk * 32) * PSTR;
#pragma unroll
    for (int r = 0; r < 16; ++r) {
        int jr = (r & 3) + 8 * (r >> 2) + 4 * hi;
        prow[(size_t)jr * PSTR + lo] = y[r];
    }
    if (lane < 32) prow[(size_t)lane * PSTR + 32] = deg;
}

// ---------------- prep: x_in [32][8192] -> master [j][32] + permuted bf16 ----------------
__global__ __launch_bounds__(256) void k_prep(const float* __restrict__ xin,
                                              float* __restrict__ xm,
                                              unsigned short* __restrict__ kq,
                                              unsigned short* __restrict__ vv) {
    const int j = blockIdx.x * 256 + threadIdx.x;
    float xv[DIM];
#pragma unroll
    for (int d = 0; d < DIM; ++d) xv[d] = xin[(size_t)d * NPIX + j];

    float4* xmr = (float4*)(xm + (size_t)j * DIM);
#pragma unroll
    for (int q = 0; q < 8; ++q)
        xmr[q] = make_float4(xv[4*q], xv[4*q+1], xv[4*q+2], xv[4*q+3]);

    uint4* kq4 = (uint4*)kq;
#pragma unroll
    for (int ks = 0; ks < 2; ++ks)
#pragma unroll
        for (int h = 0; h < 2; ++h) {
            const int b = ks * 16 + h * 8;
            unsigned w0 = (unsigned)f2bf(xv[b+0]*ALPHA) | ((unsigned)f2bf(xv[b+1]*ALPHA) << 16);
            unsigned w1 = (unsigned)f2bf(xv[b+2]*ALPHA) | ((unsigned)f2bf(xv[b+3]*ALPHA) << 16);
            unsigned w2 = (unsigned)f2bf(xv[b+4]*ALPHA) | ((unsigned)f2bf(xv[b+5]*ALPHA) << 16);
            unsigned w3 = (unsigned)f2bf(xv[b+6]*ALPHA) | ((unsigned)f2bf(xv[b+7]*ALPHA) << 16);
            kq4[(j >> 5) * 128 + ks * 64 + h * 32 + (j & 31)] = make_uint4(w0, w1, w2, w3);
        }

    const int vbase = (j >> 5) * 1024 + ((j >> 4) & 1) * 512 + ((j >> 3) & 1) * 256 + (j & 7);
#pragma unroll
    for (int d = 0; d < DIM; ++d) vv[vbase + d * 8] = f2bf(xv[d]);
}

// ---------------- reduce partials + blend + regenerate operand arrays ----------------
__global__ __launch_bounds__(256) void k_upd(const float* __restrict__ part,
                                             const float* __restrict__ xm,
                                             float* __restrict__ xm_next,
                                             unsigned short* __restrict__ kq,
                                             unsigned short* __restrict__ vv,
                                             float* __restrict__ out,
                                             int last) {
    const int j = blockIdx.x * 256 + threadIdx.x;
    float y[DIM];
#pragma unroll
    for (int d = 0; d < DIM; ++d) y[d] = 0.f;
    float dg = 0.f;
    for (int c = 0; c < SCH; ++c) {
        const float* pr = part + ((size_t)c * NPIX + j) * PSTR;
        const float4* p4 = (const float4*)pr;
#pragma unroll
        for (int q = 0; q < 8; ++q) {
            float4 v = p4[q];
            y[4*q]   += v.x; y[4*q+1] += v.y; y[4*q+2] += v.z; y[4*q+3] += v.w;
        }
        dg += pr[32];
    }
    const float inv = 0.5f / dg;

    const float4* xr = (const float4*)(xm + (size_t)j * DIM);
    float xn[DIM];
#pragma unroll
    for (int q = 0; q < 8; ++q) {
        float4 v = xr[q];
        xn[4*q]   = fmaf(y[4*q],   inv, 0.5f * v.x);
        xn[4*q+1] = fmaf(y[4*q+1], inv, 0.5f * v.y);
        xn[4*q+2] = fmaf(y[4*q+2], inv, 0.5f * v.z);
        xn[4*q+3] = fmaf(y[4*q+3], inv, 0.5f * v.w);
    }

    if (last) {
#pragma unroll
        for (int d = 0; d < DIM; ++d) out[(size_t)d * NPIX + j] = xn[d];
        return;
    }

    float4* xw = (float4*)(xm_next + (size_t)j * DIM);
#pragma unroll
    for (int q = 0; q < 8; ++q)
        xw[q] = make_float4(xn[4*q], xn[4*q+1], xn[4*q+2], xn[4*q+3]);

    uint4* kq4 = (uint4*)kq;
#pragma unroll
    for (int ks = 0; ks < 2; ++ks)
#pragma unroll
        for (int h = 0; h < 2; ++h) {
            const int b = ks * 16 + h * 8;
            unsigned w0 = (unsigned)f2bf(xn[b+0]*ALPHA) | ((unsigned)f2bf(xn[b+1]*ALPHA) << 16);
            unsigned w1 = (unsigned)f2bf(xn[b+2]*ALPHA) | ((unsigned)f2bf(xn[b+3]*ALPHA) << 16);
            unsigned w2 = (unsigned)f2bf(xn[b+4]*ALPHA) | ((unsigned)f2bf(xn[b+5]*ALPHA) << 16);
            unsigned w3 = (unsigned)f2bf(xn[b+6]*ALPHA) | ((unsigned)f2bf(xn[b+7]*ALPHA) << 16);
            kq4[(j >> 5) * 128 + ks * 64 + h * 32 + (j & 31)] = make_uint4(w0, w1, w2, w3);
        }

    const int vbase = (j >> 5) * 1024 + ((j >> 4) & 1) * 512 + ((j >> 3) & 1) * 256 + (j & 7);
#pragma unroll
    for (int d = 0; d < DIM; ++d) vv[vbase + d * 8] = f2bf(xn[d]);
}

extern "C" void kernel_launch(void* const* d_in, const int* in_sizes, int n_in,
                              void* d_out, int out_size, void* d_ws, size_t ws_size,
                              hipStream_t stream) {
    const float* x_in = (const float*)d_in[0];
    float* out = (float*)d_out;

    const size_t nd = (size_t)NPIX * DIM;          // 262144
    float* xmA = (float*)d_ws;
    float* xmB = xmA + nd;
    float* part = xmB + nd;                        // 8*8192*36 floats
    unsigned short* kq = (unsigned short*)(part + (size_t)SCH * NPIX * PSTR);
    unsigned short* vv = kq + nd;

    k_prep<<<NPIX / 256, 256, 0, stream>>>(x_in, xmA, kq, vv);

    for (int it = 0; it < NITER; ++it) {
        const int last = (it == NITER - 1);
        k_ms<<<dim3(NPIX / (32 * WAVES), SCH), 256, 0, stream>>>(kq, vv, part);
        k_upd<<<NPIX / 256, 256, 0, stream>>>(part, xmA, xmB, kq, vv, out, last);
        float* t = xmA; xmA = xmB; xmB = t;
    }
}

// Round 3
// 139.143 us; speedup vs baseline: 7.4425x; 1.1833x over previous
//
#include <hip/hip_runtime.h>
#include <hip/hip_bf16.h>
#include <math.h>

// Mean-shift as attention (see round 2). This round:
//  - k_ms: global_load_lds staging (width 16), double-buffered 32KB halves,
//    counted s_waitcnt vmcnt(8) + raw s_barrier pipeline (T3/T4-lite).
//  - k_upd: 4 threads per column j (32768 threads) for latency hiding.

typedef short bf16x8 __attribute__((ext_vector_type(8)));
typedef float f32x16 __attribute__((ext_vector_type(16)));
typedef int v2i __attribute__((ext_vector_type(2)));

#define NPIX 8192
#define DIM 32
#define NITER 5
#define SCH 8                 // i-chunks (grid.y)
#define CHUNK (NPIX / SCH)    // 1024 i per WG
#define HALF 256              // i per LDS stage
#define HALVES (CHUNK / HALF) // 4
#define WAVES 4               // waves per WG (128 j per WG)
#define PSTR 36               // partial row stride (32 y + deg + pad)
#define ALPHA 0.8493219f      // sqrt(0.5 * log2(e))

#if __has_builtin(__builtin_amdgcn_exp2f)
#define EXP2(x) __builtin_amdgcn_exp2f(x)
#else
#define EXP2(x) exp2f(x)
#endif

#if __has_builtin(__builtin_amdgcn_global_load_lds)
#define HAS_GLDS 1
#else
#define HAS_GLDS 0
#endif

__device__ __forceinline__ void glds16(const uint4* g, uint4* l) {
#if HAS_GLDS
    __builtin_amdgcn_global_load_lds((const __attribute__((address_space(1))) void*)g,
                                     (__attribute__((address_space(3))) void*)l,
                                     16, 0, 0);
#else
    *l = *g;  // unreachable fallback path (guarded at call sites)
#endif
}

__device__ inline unsigned cvtpk(float lo, float hi) {
    unsigned r;
    asm("v_cvt_pk_bf16_f32 %0, %1, %2" : "=v"(r) : "v"(lo), "v"(hi));
    return r;
}

__device__ inline void swap32(unsigned a, unsigned b, unsigned& x, unsigned& y) {
#if __has_builtin(__builtin_amdgcn_permlane32_swap)
    v2i r = __builtin_amdgcn_permlane32_swap((int)a, (int)b, false, false);
    x = (unsigned)r.x;
    y = (unsigned)r.y;
#else
    unsigned bs = __shfl_xor(b, 32);
    unsigned as = __shfl_xor(a, 32);
    int hi = (int)(threadIdx.x & 63) >> 5;
    x = hi ? bs : a;
    y = hi ? b : as;
#endif
}

__device__ inline unsigned short f2bf(float f) {  // RNE
    unsigned u = __float_as_uint(f);
    unsigned r = (u + 0x7FFFu + ((u >> 16) & 1u)) >> 16;
    return (unsigned short)r;
}

union U4 { uint4 q; bf16x8 v; };

// ---------------- main pair kernel ----------------
__global__ __launch_bounds__(256, 2) void k_ms(const unsigned short* __restrict__ kq,
                                               const unsigned short* __restrict__ vv,
                                               float* __restrict__ part) {
    __shared__ uint4 sm[4096];  // 2 bufs x (K 1024 | V 1024) uint4 = 64 KB
    const int tid = threadIdx.x;
    const int lane = tid & 63;
    const int lo = lane & 31, hi = lane >> 5;
    const int wv = tid >> 6;
    const int wbase = tid & ~63;
    const int jblk = blockIdx.x * WAVES + wv;   // 0..255
    const int chunk = blockIdx.y;               // 0..SCH-1

    const uint4* kq4 = (const uint4*)kq;
    const uint4* vv4 = (const uint4*)vv;

    // Q fragments (B-operand): lane holds col j, k-elems d = ks*16 + hi*8 + e
    U4 q0, q1;
    q0.q = kq4[jblk * 128 + lane];
    q1.q = kq4[jblk * 128 + 64 + lane];

    f32x16 y;
#pragma unroll
    for (int r = 0; r < 16; ++r) y[r] = 0.f;
    float deg = 0.f;

    const uint4* gk = kq4 + (size_t)chunk * CHUNK * 4;   // 64 B per i
    const uint4* gv = vv4 + (size_t)chunk * CHUNK * 4;

    auto STAGE = [&](int h, int b) {
        const uint4* gkh = gk + h * (HALF * 4);
        const uint4* gvh = gv + h * (HALF * 4);
        uint4* dK = sm + b * 2048 + wbase;   // wave-uniform LDS base
        uint4* dV = dK + 1024;
#pragma unroll
        for (int r = 0; r < 4; ++r) {
            glds16(gkh + r * 256 + tid, dK + r * 256);
            glds16(gvh + r * 256 + tid, dV + r * 256);
        }
    };

    STAGE(0, 0);

    for (int h = 0; h < HALVES; ++h) {
#if HAS_GLDS
        __builtin_amdgcn_s_barrier();            // prev compute done
        if (h + 1 < HALVES) {
            STAGE(h + 1, (h + 1) & 1);
            asm volatile("s_waitcnt vmcnt(8)" ::: "memory");  // buf[h] landed (mine)
        } else {
            asm volatile("s_waitcnt vmcnt(0)" ::: "memory");
        }
        __builtin_amdgcn_s_barrier();            // buf[h] landed (everyone)
#else
        __syncthreads();
        if (h + 1 < HALVES) STAGE(h + 1, (h + 1) & 1);
        __syncthreads();
#endif
        const uint4* bK = sm + ((h & 1) << 11);
        const uint4* bV = bK + 1024;
#pragma unroll
        for (int it = 0; it < HALF / 32; ++it) {
            U4 ka0, ka1, vb0, vb1;
            ka0.q = bK[it * 128 + lane];
            ka1.q = bK[it * 128 + 64 + lane];
            vb0.q = bV[it * 128 + lane];
            vb1.q = bV[it * 128 + 64 + lane];

            f32x16 s;
#pragma unroll
            for (int r = 0; r < 16; ++r) s[r] = 0.f;
            s = __builtin_amdgcn_mfma_f32_32x32x16_bf16(ka0.v, q0.v, s, 0, 0, 0);
            s = __builtin_amdgcn_mfma_f32_32x32x16_bf16(ka1.v, q1.v, s, 0, 0, 0);
            // lane holds P[i = crow(r,hi), j = lo]
            float p[16];
#pragma unroll
            for (int r = 0; r < 16; ++r) p[r] = EXP2(s[r]);

            float d0 = (p[0] + p[1]) + (p[2] + p[3]);
            float d1 = (p[4] + p[5]) + (p[6] + p[7]);
            float d2 = (p[8] + p[9]) + (p[10] + p[11]);
            float d3 = (p[12] + p[13]) + (p[14] + p[15]);
            deg += (d0 + d1) + (d2 + d3);

#pragma unroll
            for (int ks = 0; ks < 2; ++ks) {
                const float* pb = p + ks * 8;
                unsigned a0 = cvtpk(pb[0], pb[1]);
                unsigned a1 = cvtpk(pb[2], pb[3]);
                unsigned b0 = cvtpk(pb[4], pb[5]);
                unsigned b1 = cvtpk(pb[6], pb[7]);
                unsigned w01, w45, w23, w67;
                swap32(a0, b0, w01, w45);
                swap32(a1, b1, w23, w67);
                U4 pa;
                pa.q = make_uint4(w01, w23, w45, w67);
                y = __builtin_amdgcn_mfma_f32_32x32x16_bf16(
                        pa.v, (ks ? vb1.v : vb0.v), y, 0, 0, 0);
            }
        }
    }

    deg += __shfl_xor(deg, 32);

    float* prow = part + ((size_t)chunk * NPIX + (size_t)jblk * 32) * PSTR;
#pragma unroll
    for (int r = 0; r < 16; ++r) {
        int jr = (r & 3) + 8 * (r >> 2) + 4 * hi;
        prow[(size_t)jr * PSTR + lo] = y[r];
    }
    if (lane < 32) prow[(size_t)lane * PSTR + 32] = deg;
}

// ---------------- prep: x_in [32][8192] -> master [j][32] + permuted bf16 ----------------
__global__ __launch_bounds__(256) void k_prep(const float* __restrict__ xin,
                                              float* __restrict__ xm,
                                              unsigned short* __restrict__ kq,
                                              unsigned short* __restrict__ vv) {
    const int j = blockIdx.x * 256 + threadIdx.x;
    float xv[DIM];
#pragma unroll
    for (int d = 0; d < DIM; ++d) xv[d] = xin[(size_t)d * NPIX + j];

    float4* xmr = (float4*)(xm + (size_t)j * DIM);
#pragma unroll
    for (int q = 0; q < 8; ++q)
        xmr[q] = make_float4(xv[4*q], xv[4*q+1], xv[4*q+2], xv[4*q+3]);

    uint4* kq4 = (uint4*)kq;
#pragma unroll
    for (int ks = 0; ks < 2; ++ks)
#pragma unroll
        for (int h = 0; h < 2; ++h) {
            const int b = ks * 16 + h * 8;
            unsigned w0 = (unsigned)f2bf(xv[b+0]*ALPHA) | ((unsigned)f2bf(xv[b+1]*ALPHA) << 16);
            unsigned w1 = (unsigned)f2bf(xv[b+2]*ALPHA) | ((unsigned)f2bf(xv[b+3]*ALPHA) << 16);
            unsigned w2 = (unsigned)f2bf(xv[b+4]*ALPHA) | ((unsigned)f2bf(xv[b+5]*ALPHA) << 16);
            unsigned w3 = (unsigned)f2bf(xv[b+6]*ALPHA) | ((unsigned)f2bf(xv[b+7]*ALPHA) << 16);
            kq4[(j >> 5) * 128 + ks * 64 + h * 32 + (j & 31)] = make_uint4(w0, w1, w2, w3);
        }

    const int vbase = (j >> 5) * 1024 + ((j >> 4) & 1) * 512 + ((j >> 3) & 1) * 256 + (j & 7);
#pragma unroll
    for (int d = 0; d < DIM; ++d) vv[vbase + d * 8] = f2bf(xv[d]);
}

// ---------------- reduce + blend + regenerate, 4 threads per j ----------------
__global__ __launch_bounds__(256) void k_upd(const float* __restrict__ part,
                                             const float* __restrict__ xm,
                                             float* __restrict__ xm_next,
                                             unsigned short* __restrict__ kq,
                                             unsigned short* __restrict__ vv,
                                             float* __restrict__ out,
                                             int last) {
    const int t = blockIdx.x * 256 + threadIdx.x;   // 0..32767
    const int j = t >> 2, q = t & 3;                // q: which 8-dim slice

    float4 ya = make_float4(0.f, 0.f, 0.f, 0.f);
    float4 yb = make_float4(0.f, 0.f, 0.f, 0.f);
    float dg = 0.f;
    for (int c = 0; c < SCH; ++c) {
        const float* pr = part + ((size_t)c * NPIX + j) * PSTR;
        const float4* p4 = (const float4*)(pr + q * 8);
        float4 a = p4[0], b = p4[1];
        ya.x += a.x; ya.y += a.y; ya.z += a.z; ya.w += a.w;
        yb.x += b.x; yb.y += b.y; yb.z += b.z; yb.w += b.w;
        dg += pr[32];                                // all 4 threads read same addr
    }
    const float inv = 0.5f / dg;

    const float4* xr = (const float4*)(xm + (size_t)j * DIM + q * 8);
    float4 v0 = xr[0], v1 = xr[1];
    float xn[8];
    xn[0] = fmaf(ya.x, inv, 0.5f * v0.x);
    xn[1] = fmaf(ya.y, inv, 0.5f * v0.y);
    xn[2] = fmaf(ya.z, inv, 0.5f * v0.z);
    xn[3] = fmaf(ya.w, inv, 0.5f * v0.w);
    xn[4] = fmaf(yb.x, inv, 0.5f * v1.x);
    xn[5] = fmaf(yb.y, inv, 0.5f * v1.y);
    xn[6] = fmaf(yb.z, inv, 0.5f * v1.z);
    xn[7] = fmaf(yb.w, inv, 0.5f * v1.w);

    if (last) {
#pragma unroll
        for (int e = 0; e < 8; ++e) out[(size_t)(q * 8 + e) * NPIX + j] = xn[e];
        return;
    }

    float4* xw = (float4*)(xm_next + (size_t)j * DIM + q * 8);
    xw[0] = make_float4(xn[0], xn[1], xn[2], xn[3]);
    xw[1] = make_float4(xn[4], xn[5], xn[6], xn[7]);

    unsigned w0 = (unsigned)f2bf(xn[0]*ALPHA) | ((unsigned)f2bf(xn[1]*ALPHA) << 16);
    unsigned w1 = (unsigned)f2bf(xn[2]*ALPHA) | ((unsigned)f2bf(xn[3]*ALPHA) << 16);
    unsigned w2 = (unsigned)f2bf(xn[4]*ALPHA) | ((unsigned)f2bf(xn[5]*ALPHA) << 16);
    unsigned w3 = (unsigned)f2bf(xn[6]*ALPHA) | ((unsigned)f2bf(xn[7]*ALPHA) << 16);
    ((uint4*)kq)[(j >> 5) * 128 + (q >> 1) * 64 + (q & 1) * 32 + (j & 31)] =
        make_uint4(w0, w1, w2, w3);

    const int vbase = (j >> 5) * 1024 + ((j >> 4) & 1) * 512 + ((j >> 3) & 1) * 256 + (j & 7);
#pragma unroll
    for (int e = 0; e < 8; ++e) vv[vbase + (q * 8 + e) * 8] = f2bf(xn[e]);
}

extern "C" void kernel_launch(void* const* d_in, const int* in_sizes, int n_in,
                              void* d_out, int out_size, void* d_ws, size_t ws_size,
                              hipStream_t stream) {
    const float* x_in = (const float*)d_in[0];
    float* out = (float*)d_out;

    const size_t nd = (size_t)NPIX * DIM;          // 262144
    float* xmA = (float*)d_ws;
    float* xmB = xmA + nd;
    float* part = xmB + nd;                        // SCH*8192*36 floats
    unsigned short* kq = (unsigned short*)(part + (size_t)SCH * NPIX * PSTR);
    unsigned short* vv = kq + nd;

    k_prep<<<NPIX / 256, 256, 0, stream>>>(x_in, xmA, kq, vv);

    for (int it = 0; it < NITER; ++it) {
        const int last = (it == NITER - 1);
        k_ms<<<dim3(NPIX / (32 * WAVES), SCH), 256, 0, stream>>>(kq, vv, part);
        k_upd<<<(NPIX * 4) / 256, 256, 0, stream>>>(part, xmA, xmB, kq, vv, out, last);
        float* t = xmA; xmA = xmB; xmB = t;
    }
}

// Round 4
// 129.148 us; speedup vs baseline: 8.0185x; 1.0774x over previous
//
#include <hip/hip_runtime.h>
#include <hip/hip_bf16.h>
#include <math.h>

// Mean-shift as attention. Round 4:
//  - SCH=16 chunks, HALF=128 -> 32KB LDS/WG, 1024 WGs = 4 WGs/CU (4 waves/SIMD)
//  - deg computed by MFMA with all-ones B operand (off the VALU critical path)
//  - hoisted zero accumulator for the S-MFMA
// K and Q both scaled by ALPHA=sqrt(0.5*log2 e) so the inner loop is exp2 only.
// Swapped QK^T (mfma(K,Q)) keeps P lane-local; cvt_pk+permlane32_swap builds
// the PV A-fragment in-register. Operand arrays are pre-permuted fragment-order
// (A-layout for K, B-layout for V) so staging is linear and reads conflict-free.

typedef short bf16x8 __attribute__((ext_vector_type(8)));
typedef float f32x16 __attribute__((ext_vector_type(16)));
typedef int v2i __attribute__((ext_vector_type(2)));

#define NPIX 8192
#define DIM 32
#define NITER 5
#define SCH 16                // i-chunks (grid.y)
#define CHUNK (NPIX / SCH)    // 512 i per WG
#define HALF 128              // i per LDS stage
#define HALVES (CHUNK / HALF) // 4
#define WAVES 4               // waves per WG (128 j per WG)
#define PSTR 36               // partial row stride (32 y + deg + pad)
#define ALPHA 0.8493219f      // sqrt(0.5 * log2(e))

#if __has_builtin(__builtin_amdgcn_exp2f)
#define EXP2(x) __builtin_amdgcn_exp2f(x)
#else
#define EXP2(x) exp2f(x)
#endif

#if __has_builtin(__builtin_amdgcn_global_load_lds)
#define HAS_GLDS 1
#else
#define HAS_GLDS 0
#endif

__device__ __forceinline__ void glds16(const uint4* g, uint4* l) {
#if HAS_GLDS
    __builtin_amdgcn_global_load_lds((const __attribute__((address_space(1))) void*)g,
                                     (__attribute__((address_space(3))) void*)l,
                                     16, 0, 0);
#else
    *l = *g;
#endif
}

__device__ inline unsigned cvtpk(float lo, float hi) {
    unsigned r;
    asm("v_cvt_pk_bf16_f32 %0, %1, %2" : "=v"(r) : "v"(lo), "v"(hi));
    return r;
}

__device__ inline void swap32(unsigned a, unsigned b, unsigned& x, unsigned& y) {
#if __has_builtin(__builtin_amdgcn_permlane32_swap)
    v2i r = __builtin_amdgcn_permlane32_swap((int)a, (int)b, false, false);
    x = (unsigned)r.x;
    y = (unsigned)r.y;
#else
    unsigned bs = __shfl_xor(b, 32);
    unsigned as = __shfl_xor(a, 32);
    int hi = (int)(threadIdx.x & 63) >> 5;
    x = hi ? bs : a;
    y = hi ? b : as;
#endif
}

__device__ inline unsigned short f2bf(float f) {  // RNE
    unsigned u = __float_as_uint(f);
    unsigned r = (u + 0x7FFFu + ((u >> 16) & 1u)) >> 16;
    return (unsigned short)r;
}

union U4 { uint4 q; bf16x8 v; };

// ---------------- main pair kernel ----------------
__global__ __launch_bounds__(256, 4) void k_ms(const unsigned short* __restrict__ kq,
                                               const unsigned short* __restrict__ vv,
                                               float* __restrict__ part) {
    __shared__ uint4 sm[2048];  // 2 bufs x (K 512 | V 512) uint4 = 32 KB
    const int tid = threadIdx.x;
    const int lane = tid & 63;
    const int lo = lane & 31, hi = lane >> 5;
    const int wv = tid >> 6;
    const int wbase = tid & ~63;
    const int jblk = blockIdx.x * WAVES + wv;   // 0..255
    const int chunk = blockIdx.y;               // 0..SCH-1

    const uint4* kq4 = (const uint4*)kq;
    const uint4* vv4 = (const uint4*)vv;

    // Q fragments (B-operand): lane holds col j, k-elems d = ks*16 + hi*8 + e
    U4 q0, q1;
    q0.q = kq4[jblk * 128 + lane];
    q1.q = kq4[jblk * 128 + 64 + lane];

    U4 ones;
    ones.q = make_uint4(0x3F803F80u, 0x3F803F80u, 0x3F803F80u, 0x3F803F80u);

    f32x16 z16;
#pragma unroll
    for (int r = 0; r < 16; ++r) z16[r] = 0.f;
    f32x16 y = z16;
    f32x16 dg16 = z16;

    const uint4* gk = kq4 + (size_t)chunk * CHUNK * 4;   // 64 B per i
    const uint4* gv = vv4 + (size_t)chunk * CHUNK * 4;

    auto STAGE = [&](int h, int b) {
        const uint4* gkh = gk + h * (HALF * 4);
        const uint4* gvh = gv + h * (HALF * 4);
        uint4* dK = sm + b * 1024 + wbase;   // wave-uniform LDS base
        uint4* dV = dK + 512;
#pragma unroll
        for (int r = 0; r < 2; ++r) {
            glds16(gkh + r * 256 + tid, dK + r * 256);
            glds16(gvh + r * 256 + tid, dV + r * 256);
        }
    };

    STAGE(0, 0);

    for (int h = 0; h < HALVES; ++h) {
#if HAS_GLDS
        __builtin_amdgcn_s_barrier();            // prev compute done
        if (h + 1 < HALVES) {
            STAGE(h + 1, (h + 1) & 1);
            asm volatile("s_waitcnt vmcnt(4)" ::: "memory");  // buf[h] landed (mine)
        } else {
            asm volatile("s_waitcnt vmcnt(0)" ::: "memory");
        }
        __builtin_amdgcn_s_barrier();            // buf[h] landed (everyone)
#else
        __syncthreads();
        if (h + 1 < HALVES) STAGE(h + 1, (h + 1) & 1);
        __syncthreads();
#endif
        const uint4* bK = sm + ((h & 1) << 10);
        const uint4* bV = bK + 512;
#pragma unroll
        for (int it = 0; it < HALF / 32; ++it) {
            U4 ka0, ka1, vb0, vb1;
            ka0.q = bK[it * 128 + lane];
            ka1.q = bK[it * 128 + 64 + lane];
            vb0.q = bV[it * 128 + lane];
            vb1.q = bV[it * 128 + 64 + lane];

            f32x16 s;
            s = __builtin_amdgcn_mfma_f32_32x32x16_bf16(ka0.v, q0.v, z16, 0, 0, 0);
            s = __builtin_amdgcn_mfma_f32_32x32x16_bf16(ka1.v, q1.v, s, 0, 0, 0);
            // lane holds P[i = crow(r,hi), j = lo]
            float p[16];
#pragma unroll
            for (int r = 0; r < 16; ++r) p[r] = EXP2(s[r]);

#pragma unroll
            for (int ks = 0; ks < 2; ++ks) {
                const float* pb = p + ks * 8;
                unsigned a0 = cvtpk(pb[0], pb[1]);
                unsigned a1 = cvtpk(pb[2], pb[3]);
                unsigned b0 = cvtpk(pb[4], pb[5]);
                unsigned b1 = cvtpk(pb[6], pb[7]);
                unsigned w01, w45, w23, w67;
                swap32(a0, b0, w01, w45);
                swap32(a1, b1, w23, w67);
                U4 pa;
                pa.q = make_uint4(w01, w23, w45, w67);
                y = __builtin_amdgcn_mfma_f32_32x32x16_bf16(
                        pa.v, (ks ? vb1.v : vb0.v), y, 0, 0, 0);
                dg16 = __builtin_amdgcn_mfma_f32_32x32x16_bf16(
                        pa.v, ones.v, dg16, 0, 0, 0);
            }
        }
    }

    float* prow = part + ((size_t)chunk * NPIX + (size_t)jblk * 32) * PSTR;
#pragma unroll
    for (int r = 0; r < 16; ++r) {
        int jr = (r & 3) + 8 * (r >> 2) + 4 * hi;
        prow[(size_t)jr * PSTR + lo] = y[r];
        if (lo == 0) prow[(size_t)jr * PSTR + 32] = dg16[r];
    }
}

// ---------------- prep: x_in [32][8192] -> master [j][32] + permuted bf16 ----------------
__global__ __launch_bounds__(256) void k_prep(const float* __restrict__ xin,
                                              float* __restrict__ xm,
                                              unsigned short* __restrict__ kq,
                                              unsigned short* __restrict__ vv) {
    const int j = blockIdx.x * 256 + threadIdx.x;
    float xv[DIM];
#pragma unroll
    for (int d = 0; d < DIM; ++d) xv[d] = xin[(size_t)d * NPIX + j];

    float4* xmr = (float4*)(xm + (size_t)j * DIM);
#pragma unroll
    for (int q = 0; q < 8; ++q)
        xmr[q] = make_float4(xv[4*q], xv[4*q+1], xv[4*q+2], xv[4*q+3]);

    uint4* kq4 = (uint4*)kq;
#pragma unroll
    for (int ks = 0; ks < 2; ++ks)
#pragma unroll
        for (int h = 0; h < 2; ++h) {
            const int b = ks * 16 + h * 8;
            unsigned w0 = (unsigned)f2bf(xv[b+0]*ALPHA) | ((unsigned)f2bf(xv[b+1]*ALPHA) << 16);
            unsigned w1 = (unsigned)f2bf(xv[b+2]*ALPHA) | ((unsigned)f2bf(xv[b+3]*ALPHA) << 16);
            unsigned w2 = (unsigned)f2bf(xv[b+4]*ALPHA) | ((unsigned)f2bf(xv[b+5]*ALPHA) << 16);
            unsigned w3 = (unsigned)f2bf(xv[b+6]*ALPHA) | ((unsigned)f2bf(xv[b+7]*ALPHA) << 16);
            kq4[(j >> 5) * 128 + ks * 64 + h * 32 + (j & 31)] = make_uint4(w0, w1, w2, w3);
        }

    const int vbase = (j >> 5) * 1024 + ((j >> 4) & 1) * 512 + ((j >> 3) & 1) * 256 + (j & 7);
#pragma unroll
    for (int d = 0; d < DIM; ++d) vv[vbase + d * 8] = f2bf(xv[d]);
}

// ---------------- reduce + blend + regenerate, 4 threads per j ----------------
__global__ __launch_bounds__(256) void k_upd(const float* __restrict__ part,
                                             const float* __restrict__ xm,
                                             float* __restrict__ xm_next,
                                             unsigned short* __restrict__ kq,
                                             unsigned short* __restrict__ vv,
                                             float* __restrict__ out,
                                             int last) {
    const int t = blockIdx.x * 256 + threadIdx.x;   // 0..32767
    const int j = t >> 2, q = t & 3;                // q: which 8-dim slice

    float4 ya = make_float4(0.f, 0.f, 0.f, 0.f);
    float4 yb = make_float4(0.f, 0.f, 0.f, 0.f);
    float dg = 0.f;
    for (int c = 0; c < SCH; ++c) {
        const float* pr = part + ((size_t)c * NPIX + j) * PSTR;
        const float4* p4 = (const float4*)(pr + q * 8);
        float4 a = p4[0], b = p4[1];
        ya.x += a.x; ya.y += a.y; ya.z += a.z; ya.w += a.w;
        yb.x += b.x; yb.y += b.y; yb.z += b.z; yb.w += b.w;
        dg += pr[32];                                // all 4 threads read same addr
    }
    const float inv = 0.5f / dg;

    const float4* xr = (const float4*)(xm + (size_t)j * DIM + q * 8);
    float4 v0 = xr[0], v1 = xr[1];
    float xn[8];
    xn[0] = fmaf(ya.x, inv, 0.5f * v0.x);
    xn[1] = fmaf(ya.y, inv, 0.5f * v0.y);
    xn[2] = fmaf(ya.z, inv, 0.5f * v0.z);
    xn[3] = fmaf(ya.w, inv, 0.5f * v0.w);
    xn[4] = fmaf(yb.x, inv, 0.5f * v1.x);
    xn[5] = fmaf(yb.y, inv, 0.5f * v1.y);
    xn[6] = fmaf(yb.z, inv, 0.5f * v1.z);
    xn[7] = fmaf(yb.w, inv, 0.5f * v1.w);

    if (last) {
#pragma unroll
        for (int e = 0; e < 8; ++e) out[(size_t)(q * 8 + e) * NPIX + j] = xn[e];
        return;
    }

    float4* xw = (float4*)(xm_next + (size_t)j * DIM + q * 8);
    xw[0] = make_float4(xn[0], xn[1], xn[2], xn[3]);
    xw[1] = make_float4(xn[4], xn[5], xn[6], xn[7]);

    unsigned w0 = (unsigned)f2bf(xn[0]*ALPHA) | ((unsigned)f2bf(xn[1]*ALPHA) << 16);
    unsigned w1 = (unsigned)f2bf(xn[2]*ALPHA) | ((unsigned)f2bf(xn[3]*ALPHA) << 16);
    unsigned w2 = (unsigned)f2bf(xn[4]*ALPHA) | ((unsigned)f2bf(xn[5]*ALPHA) << 16);
    unsigned w3 = (unsigned)f2bf(xn[6]*ALPHA) | ((unsigned)f2bf(xn[7]*ALPHA) << 16);
    ((uint4*)kq)[(j >> 5) * 128 + (q >> 1) * 64 + (q & 1) * 32 + (j & 31)] =
        make_uint4(w0, w1, w2, w3);

    const int vbase = (j >> 5) * 1024 + ((j >> 4) & 1) * 512 + ((j >> 3) & 1) * 256 + (j & 7);
#pragma unroll
    for (int e = 0; e < 8; ++e) vv[vbase + (q * 8 + e) * 8] = f2bf(xn[e]);
}

extern "C" void kernel_launch(void* const* d_in, const int* in_sizes, int n_in,
                              void* d_out, int out_size, void* d_ws, size_t ws_size,
                              hipStream_t stream) {
    const float* x_in = (const float*)d_in[0];
    float* out = (float*)d_out;

    const size_t nd = (size_t)NPIX * DIM;          // 262144
    float* xmA = (float*)d_ws;
    float* xmB = xmA + nd;
    float* part = xmB + nd;                        // SCH*8192*36 floats
    unsigned short* kq = (unsigned short*)(part + (size_t)SCH * NPIX * PSTR);
    unsigned short* vv = kq + nd;

    k_prep<<<NPIX / 256, 256, 0, stream>>>(x_in, xmA, kq, vv);

    for (int it = 0; it < NITER; ++it) {
        const int last = (it == NITER - 1);
        k_ms<<<dim3(NPIX / (32 * WAVES), SCH), 256, 0, stream>>>(kq, vv, part);
        k_upd<<<(NPIX * 4) / 256, 256, 0, stream>>>(part, xmA, xmB, kq, vv, out, last);
        float* t = xmA; xmA = xmB; xmB = t;
    }
}